// Round 1
// baseline (547.304 us; speedup 1.0000x reference)
//
#include <hip/hip_runtime.h>

typedef unsigned short u16;
typedef __attribute__((ext_vector_type(8))) short s16x8;
typedef __attribute__((ext_vector_type(4))) float f32x4;

// Pcat column offsets (bf16 projection buffer, 4096 rows x 4096 cols)
#define C_QSA 0
#define C_KSA 512
#define C_VSA 1024
#define C_QA  1536
#define C_KA  2048
#define C_QR  2560
#define C_KR  3072
#define C_SV  3584
#define LDP   4096
#define NROWS 4096   // B*S

__device__ __forceinline__ u16 f2bf(float f) {
    union { float f; unsigned u; } v; v.f = f;
    return (u16)((v.u + 0x7FFFu + ((v.u >> 16) & 1u)) >> 16);  // RNE
}
__device__ __forceinline__ float bf2f(u16 h) {
    union { unsigned u; float f; } v; v.u = ((unsigned)h) << 16; return v.f;
}
__device__ __forceinline__ float fexp(float y) {          // e^y
    return __builtin_exp2f(y * 1.4426950408889634f);
}
__device__ __forceinline__ float ftanh(float x) {         // exact formula, f32
    float e = __builtin_exp2f(x * 2.885390081777927f);    // exp(2x)
    return 1.f - 2.f / (e + 1.f);
}
__device__ __forceinline__ f32x4 mfma16(s16x8 a, s16x8 b, f32x4 c) {
    return __builtin_amdgcn_mfma_f32_16x16x32_bf16(a, b, c, 0, 0, 0);
}

// ---------------- converts / transposes ----------------

__global__ void cvt_f32_bf16(const float* __restrict__ in, u16* __restrict__ out, int n) {
    int i = (blockIdx.x * 256 + threadIdx.x) * 8;
    if (i >= n) return;
    float4 a = *(const float4*)(in + i);
    float4 b = *(const float4*)(in + i + 4);
    s16x8 o;
    o[0] = (short)f2bf(a.x); o[1] = (short)f2bf(a.y);
    o[2] = (short)f2bf(a.z); o[3] = (short)f2bf(a.w);
    o[4] = (short)f2bf(b.x); o[5] = (short)f2bf(b.y);
    o[6] = (short)f2bf(b.z); o[7] = (short)f2bf(b.w);
    *(s16x8*)(out + i) = o;
}

// Wt[n][k] = W[k][n], f32 -> bf16.  (Bt input for the GEMMs.)
__global__ void transpose_cvt(const float* __restrict__ W, u16* __restrict__ Wt, int K, int N) {
    int idx = blockIdx.x * 256 + threadIdx.x;
    int n = idx / K, k = idx - n * K;
    Wt[(size_t)n * K + k] = f2bf(W[(size_t)k * N + n]);
}

// Vt[b][h][d][s] = Pcat[b*1024+s][colOff + h*64 + d]   (2^21 elements)
__global__ void transpose_v(const u16* __restrict__ P, u16* __restrict__ Vt, int colOff) {
    int idx = blockIdx.x * 256 + threadIdx.x;
    int s = idx & 1023;
    int d = (idx >> 10) & 63;
    int h = (idx >> 16) & 7;
    int b = idx >> 19;
    Vt[idx] = P[((size_t)((b << 10) + s)) * LDP + colOff + (h << 6) + d];
}

// ---------------- RoPE (in-place on Pcat regions QSA,KSA,QA,KA) ----------------

__global__ void rope_kernel(u16* __restrict__ P, const float* __restrict__ fcos,
                            const float* __restrict__ fsin) {
    int idx = blockIdx.x * 256 + threadIdx.x;   // NROWS * 1024 pairs
    int row = idx >> 10;
    int rem = idx & 1023;
    int region = rem >> 8;                      // 0..3 -> {0,512,1536,2048}
    int pr = rem & 255;
    int head = pr >> 5, p = pr & 31;
    int off = (region + (region >> 1)) * 512;
    int col = off + head * 64 + 2 * p;
    int s = row & 1023;
    float c = fcos[s * 32 + p], sn = fsin[s * 32 + p];
    u16* ptr = P + (size_t)row * LDP + col;
    float xr = bf2f(ptr[0]), xi = bf2f(ptr[1]);
    ptr[0] = f2bf(xr * c - xi * sn);
    ptr[1] = f2bf(xr * sn + xi * c);
}

// ---------------- GEMM: C[M=4096][N] = A[M][K] @ Bt[N][K]^T ----------------
// 128x128 tile, BK=32, 4 waves (2x2 of 64x64), 16x16x32 bf16 MFMA.

template<bool OUT_BF16>
__global__ __launch_bounds__(256) void gemm_bf16(
    const u16* __restrict__ A, const u16* __restrict__ A2, int lda, int nswitch,
    const u16* __restrict__ Bt, int ldb,
    void* __restrict__ Cp, int ldc, int ccolOff, int K)
{
    __shared__ u16 As[128][40];
    __shared__ u16 Bs[128][40];
    const int tid = threadIdx.x;
    const int m0 = blockIdx.x * 128, n0 = blockIdx.y * 128;
    const u16* Ause = (A2 != nullptr && n0 >= nswitch) ? A2 : A;
    const int w = tid >> 6, lane = tid & 63;
    const int wm = (w >> 1) * 64, wn = (w & 1) * 64;
    const int lr = lane & 15, lg = lane >> 4;
    f32x4 acc[4][4] = {};

    for (int k0 = 0; k0 < K; k0 += 32) {
#pragma unroll
        for (int it = 0; it < 2; ++it) {
            int idx = tid + it * 256;
            int m = idx >> 2, seg = (idx & 3) * 8;
            *(s16x8*)&As[m][seg] = *(const s16x8*)&Ause[(size_t)(m0 + m) * lda + k0 + seg];
            *(s16x8*)&Bs[m][seg] = *(const s16x8*)&Bt[(size_t)(n0 + m) * ldb + k0 + seg];
        }
        __syncthreads();
        s16x8 af[4], bfr[4];
#pragma unroll
        for (int t = 0; t < 4; ++t) {
            af[t]  = *(const s16x8*)&As[wm + t * 16 + lr][lg * 8];
            bfr[t] = *(const s16x8*)&Bs[wn + t * 16 + lr][lg * 8];
        }
#pragma unroll
        for (int i = 0; i < 4; ++i)
#pragma unroll
            for (int j = 0; j < 4; ++j)
                acc[i][j] = mfma16(af[i], bfr[j], acc[i][j]);
        __syncthreads();
    }
#pragma unroll
    for (int i = 0; i < 4; ++i)
#pragma unroll
        for (int j = 0; j < 4; ++j)
#pragma unroll
            for (int r = 0; r < 4; ++r) {
                int row = m0 + wm + i * 16 + lg * 4 + r;
                int col = n0 + wn + j * 16 + lr;
                float val = acc[i][j][r];
                if (OUT_BF16)
                    ((u16*)Cp)[(size_t)row * ldc + ccolOff + col] = f2bf(val);
                else
                    ((float*)Cp)[(size_t)row * ldc + ccolOff + col] = val;
            }
}

// ---------------- SA flash attention: 1 wave per (b,h,16 q-rows) ----------------

__global__ __launch_bounds__(64) void attn_sa(u16* __restrict__ P, const u16* __restrict__ Vt) {
    const int i0 = blockIdx.x * 16;
    const int h = blockIdx.y, b = blockIdx.z;
    const int lane = threadIdx.x, lr = lane & 15, lg = lane >> 4;
    const size_t rowBase = (size_t)b * 1024;
    __shared__ u16 pl[16][40];

    s16x8 qf[2];
    {
        const u16* q = P + (rowBase + i0 + lr) * LDP + (C_QSA + h * 64) + lg * 8;
        qf[0] = *(const s16x8*)q;
        qf[1] = *(const s16x8*)(q + 32);
    }
    f32x4 osum[4] = {};
    float m[4], l[4];
#pragma unroll
    for (int r = 0; r < 4; ++r) { m[r] = -1e30f; l[r] = 0.f; }

    const u16* Kbase = P + rowBase * LDP + (C_KSA + h * 64);
    const u16* Vb = Vt + ((size_t)(b * 8 + h)) * 65536;
    const int njt = (i0 + 15) / 32 + 1;

    for (int jt = 0; jt < njt; ++jt) {
        int j0 = jt * 32;
        f32x4 sc[2] = {{0.f,0.f,0.f,0.f},{0.f,0.f,0.f,0.f}};
#pragma unroll
        for (int sub = 0; sub < 2; ++sub) {
            const u16* kp = Kbase + (size_t)(j0 + sub * 16 + lr) * LDP + lg * 8;
            s16x8 kf0 = *(const s16x8*)kp;
            s16x8 kf1 = *(const s16x8*)(kp + 32);
            sc[sub] = mfma16(qf[0], kf0, sc[sub]);
            sc[sub] = mfma16(qf[1], kf1, sc[sub]);
        }
#pragma unroll
        for (int sub = 0; sub < 2; ++sub)
#pragma unroll
            for (int r = 0; r < 4; ++r) {
                int row = i0 + lg * 4 + r;
                int col = j0 + sub * 16 + lr;
                float v = sc[sub][r] * 0.125f;
                sc[sub][r] = (col <= row) ? v : -1e30f;
            }
        float p0[4], p1[4], f[4];
#pragma unroll
        for (int r = 0; r < 4; ++r) {
            float v = fmaxf(sc[0][r], sc[1][r]);
            v = fmaxf(v, __shfl_xor(v, 1));
            v = fmaxf(v, __shfl_xor(v, 2));
            v = fmaxf(v, __shfl_xor(v, 4));
            v = fmaxf(v, __shfl_xor(v, 8));
            float mn = fmaxf(m[r], v);
            f[r] = fexp(m[r] - mn);
            m[r] = mn;
            p0[r] = fexp(sc[0][r] - mn);
            p1[r] = fexp(sc[1][r] - mn);
            float rs = p0[r] + p1[r];
            rs += __shfl_xor(rs, 1); rs += __shfl_xor(rs, 2);
            rs += __shfl_xor(rs, 4); rs += __shfl_xor(rs, 8);
            l[r] = l[r] * f[r] + rs;
        }
#pragma unroll
        for (int ds = 0; ds < 4; ++ds)
#pragma unroll
            for (int r = 0; r < 4; ++r) osum[ds][r] *= f[r];

        __syncthreads();
#pragma unroll
        for (int r = 0; r < 4; ++r) {
            pl[lg * 4 + r][lr]      = f2bf(p0[r]);
            pl[lg * 4 + r][16 + lr] = f2bf(p1[r]);
        }
        __syncthreads();
        s16x8 pa = *(const s16x8*)&pl[lr][lg * 8];
#pragma unroll
        for (int ds = 0; ds < 4; ++ds) {
            const u16* vp = Vb + (size_t)(ds * 16 + lr) * 1024 + j0 + lg * 8;
            s16x8 vb = *(const s16x8*)vp;
            osum[ds] = mfma16(pa, vb, osum[ds]);
        }
    }
#pragma unroll
    for (int ds = 0; ds < 4; ++ds)
#pragma unroll
        for (int r = 0; r < 4; ++r) {
            int row = i0 + lg * 4 + r;
            float v = osum[ds][r] / l[r];
            P[(rowBase + row) * LDP + (C_QSA + h * 64) + ds * 16 + lr] = f2bf(v);
        }
}

// ---------------- RA attention, fused with tanh relation stream ----------------

__global__ __launch_bounds__(64) void attn_ra(u16* __restrict__ P, const u16* __restrict__ SVt,
                                              const float* __restrict__ wr) {
    const int i0 = blockIdx.x * 16;
    const int h = blockIdx.y, b = blockIdx.z;
    const int lane = threadIdx.x, lr = lane & 15, lg = lane >> 4;
    const size_t rowBase = (size_t)b * 1024;
    __shared__ u16 pl[16][40];

    s16x8 qf[2];
    {
        const u16* q = P + (rowBase + i0 + lr) * LDP + (C_QA + h * 64) + lg * 8;
        qf[0] = *(const s16x8*)q;
        qf[1] = *(const s16x8*)(q + 32);
    }
    s16x8 qrf[8][2];
#pragma unroll
    for (int r8 = 0; r8 < 8; ++r8) {
        const u16* q = P + (rowBase + i0 + lr) * LDP + (C_QR + r8 * 64) + lg * 8;
        qrf[r8][0] = *(const s16x8*)q;
        qrf[r8][1] = *(const s16x8*)(q + 32);
    }
    f32x4 osum[4] = {};
    float relm[4][8] = {};
    float m[4], l[4];
#pragma unroll
    for (int r = 0; r < 4; ++r) { m[r] = -1e30f; l[r] = 0.f; }

    const u16* Kbase  = P + rowBase * LDP + (C_KA + h * 64);
    const u16* KRbase = P + rowBase * LDP + C_KR;
    const u16* Vb = SVt + ((size_t)(b * 8 + h)) * 65536;
    const int njt = (i0 + 15) / 32 + 1;

    for (int jt = 0; jt < njt; ++jt) {
        int j0 = jt * 32;
        f32x4 sc[2] = {{0.f,0.f,0.f,0.f},{0.f,0.f,0.f,0.f}};
#pragma unroll
        for (int sub = 0; sub < 2; ++sub) {
            const u16* kp = Kbase + (size_t)(j0 + sub * 16 + lr) * LDP + lg * 8;
            s16x8 kf0 = *(const s16x8*)kp;
            s16x8 kf1 = *(const s16x8*)(kp + 32);
            sc[sub] = mfma16(qf[0], kf0, sc[sub]);
            sc[sub] = mfma16(qf[1], kf1, sc[sub]);
        }
#pragma unroll
        for (int sub = 0; sub < 2; ++sub)
#pragma unroll
            for (int r = 0; r < 4; ++r) {
                int row = i0 + lg * 4 + r;
                int col = j0 + sub * 16 + lr;
                float v = sc[sub][r] * 0.125f;
                sc[sub][r] = (col <= row) ? v : -1e30f;
            }
        float p0[4], p1[4], f[4];
#pragma unroll
        for (int r = 0; r < 4; ++r) {
            float v = fmaxf(sc[0][r], sc[1][r]);
            v = fmaxf(v, __shfl_xor(v, 1));
            v = fmaxf(v, __shfl_xor(v, 2));
            v = fmaxf(v, __shfl_xor(v, 4));
            v = fmaxf(v, __shfl_xor(v, 8));
            float mn = fmaxf(m[r], v);
            f[r] = fexp(m[r] - mn);
            m[r] = mn;
            p0[r] = fexp(sc[0][r] - mn);
            p1[r] = fexp(sc[1][r] - mn);
            float rs = p0[r] + p1[r];
            rs += __shfl_xor(rs, 1); rs += __shfl_xor(rs, 2);
            rs += __shfl_xor(rs, 4); rs += __shfl_xor(rs, 8);
            l[r] = l[r] * f[r] + rs;
        }
#pragma unroll
        for (int ds = 0; ds < 4; ++ds)
#pragma unroll
            for (int r = 0; r < 4; ++r) osum[ds][r] *= f[r];
#pragma unroll
        for (int r = 0; r < 4; ++r)
#pragma unroll
            for (int r8 = 0; r8 < 8; ++r8) relm[r][r8] *= f[r];

        // relation tiles: rel[i,j,r8] = tanh(0.125 * qr_i . kr_j), accumulate p*rel
#pragma unroll
        for (int r8 = 0; r8 < 8; ++r8) {
            f32x4 rt[2] = {{0.f,0.f,0.f,0.f},{0.f,0.f,0.f,0.f}};
#pragma unroll
            for (int sub = 0; sub < 2; ++sub) {
                const u16* kp = KRbase + (size_t)(j0 + sub * 16 + lr) * LDP + r8 * 64 + lg * 8;
                s16x8 ka0 = *(const s16x8*)kp;
                s16x8 ka1 = *(const s16x8*)(kp + 32);
                rt[sub] = mfma16(qrf[r8][0], ka0, rt[sub]);
                rt[sub] = mfma16(qrf[r8][1], ka1, rt[sub]);
            }
#pragma unroll
            for (int r = 0; r < 4; ++r) {
                float t0 = ftanh(rt[0][r] * 0.125f);
                float t1 = ftanh(rt[1][r] * 0.125f);
                relm[r][r8] += p0[r] * t0 + p1[r] * t1;
            }
        }

        __syncthreads();
#pragma unroll
        for (int r = 0; r < 4; ++r) {
            pl[lg * 4 + r][lr]      = f2bf(p0[r]);
            pl[lg * 4 + r][16 + lr] = f2bf(p1[r]);
        }
        __syncthreads();
        s16x8 pa = *(const s16x8*)&pl[lr][lg * 8];
#pragma unroll
        for (int ds = 0; ds < 4; ++ds) {
            const u16* vp = Vb + (size_t)(ds * 16 + lr) * 1024 + j0 + lg * 8;
            s16x8 vb = *(const s16x8*)vp;
            osum[ds] = mfma16(pa, vb, osum[ds]);
        }
    }

    // reduce relm across the 16-lane group, normalize
#pragma unroll
    for (int r = 0; r < 4; ++r)
#pragma unroll
        for (int r8 = 0; r8 < 8; ++r8) {
            float v = relm[r][r8];
            v += __shfl_xor(v, 1); v += __shfl_xor(v, 2);
            v += __shfl_xor(v, 4); v += __shfl_xor(v, 8);
            relm[r][r8] = v / l[r];
        }
#pragma unroll
    for (int ds = 0; ds < 4; ++ds) {
        int d = ds * 16 + lr;
        float wrv[8];
#pragma unroll
        for (int r8 = 0; r8 < 8; ++r8) wrv[r8] = wr[h * 512 + d * 8 + r8];
#pragma unroll
        for (int r = 0; r < 4; ++r) {
            float v = osum[ds][r] / l[r];
#pragma unroll
            for (int r8 = 0; r8 < 8; ++r8) v += relm[r][r8] * wrv[r8];
            P[(rowBase + i0 + lg * 4 + r) * LDP + (C_QA + h * 64) + d] = f2bf(v);
        }
    }
}

// ---------------- launcher ----------------

extern "C" void kernel_launch(void* const* d_in, const int* in_sizes, int n_in,
                              void* d_out, int out_size, void* d_ws, size_t ws_size,
                              hipStream_t stream)
{
    const float* x     = (const float*)d_in[0];
    const float* sym   = (const float*)d_in[1];
    const float* fcos  = (const float*)d_in[2];
    const float* fsin  = (const float*)d_in[3];
    const float* w_qsa = (const float*)d_in[4];
    const float* w_ksa = (const float*)d_in[5];
    const float* w_vsa = (const float*)d_in[6];
    const float* w_osa = (const float*)d_in[7];
    const float* w_qa  = (const float*)d_in[8];
    const float* w_ka  = (const float*)d_in[9];
    const float* w_qr  = (const float*)d_in[10];
    const float* w_kr  = (const float*)d_in[11];
    const float* wr    = (const float*)d_in[12];
    const float* w_sv  = (const float*)d_in[13];
    const float* w_ora = (const float*)d_in[14];

    char* ws = (char*)d_ws;
    u16* xb    = (u16*)(ws);                                  // 8 MB
    u16* symb  = (u16*)(ws + (8u  << 20));                    // 8 MB
    u16* WcatT = (u16*)(ws + (16u << 20));                    // 8 MB (4096 x 1024)
    u16* woSaT = (u16*)(ws + (24u << 20));                    // 512 KB
    u16* woRaT = (u16*)(ws + (24u << 20) + (512u << 10));     // 512 KB
    u16* Pcat  = (u16*)(ws + (25u << 20));                    // 32 MB (4096 x 4096)
    u16* vT    = (u16*)(ws + (57u << 20));                    // 4 MB
    u16* svT   = (u16*)(ws + (61u << 20));                    // 4 MB

    // bf16 converts
    cvt_f32_bf16<<<2048, 256, 0, stream>>>(x,   xb,   4194304);
    cvt_f32_bf16<<<2048, 256, 0, stream>>>(sym, symb, 4194304);

    // transposed bf16 weights: WcatT rows [off, off+512) = W^T
    transpose_cvt<<<2048, 256, 0, stream>>>(w_qsa, WcatT + (size_t)C_QSA * 1024, 1024, 512);
    transpose_cvt<<<2048, 256, 0, stream>>>(w_ksa, WcatT + (size_t)C_KSA * 1024, 1024, 512);
    transpose_cvt<<<2048, 256, 0, stream>>>(w_vsa, WcatT + (size_t)C_VSA * 1024, 1024, 512);
    transpose_cvt<<<2048, 256, 0, stream>>>(w_qa,  WcatT + (size_t)C_QA  * 1024, 1024, 512);
    transpose_cvt<<<2048, 256, 0, stream>>>(w_ka,  WcatT + (size_t)C_KA  * 1024, 1024, 512);
    transpose_cvt<<<2048, 256, 0, stream>>>(w_qr,  WcatT + (size_t)C_QR  * 1024, 1024, 512);
    transpose_cvt<<<2048, 256, 0, stream>>>(w_kr,  WcatT + (size_t)C_KR  * 1024, 1024, 512);
    transpose_cvt<<<2048, 256, 0, stream>>>(w_sv,  WcatT + (size_t)C_SV  * 1024, 1024, 512);
    transpose_cvt<<<1024, 256, 0, stream>>>(w_osa, woSaT, 512, 512);
    transpose_cvt<<<1024, 256, 0, stream>>>(w_ora, woRaT, 512, 512);

    // fused projection GEMM: Pcat[4096][4096]; A = xb except SV columns use symb
    gemm_bf16<true><<<dim3(32, 32), 256, 0, stream>>>(
        xb, symb, 1024, C_SV, WcatT, 1024, Pcat, LDP, 0, 1024);

    // RoPE in place on q_sa, k_sa, qa, ka
    rope_kernel<<<16384, 256, 0, stream>>>(Pcat, fcos, fsin);

    // V / SV transposed copies for the PV MFMA B-operand
    transpose_v<<<8192, 256, 0, stream>>>(Pcat, vT,  C_VSA);
    transpose_v<<<8192, 256, 0, stream>>>(Pcat, svT, C_SV);

    // attention (outputs alias dead q_sa / qa column regions)
    attn_sa<<<dim3(64, 8, 4), 64, 0, stream>>>(Pcat, vT);
    attn_ra<<<dim3(64, 8, 4), 64, 0, stream>>>(Pcat, svT, wr);

    // output projections straight into f32 d_out (ldc = 1024)
    gemm_bf16<false><<<dim3(32, 4), 256, 0, stream>>>(
        Pcat + C_QSA, nullptr, LDP, 1 << 30, woSaT, 512, d_out, 1024, 0,   512);
    gemm_bf16<false><<<dim3(32, 4), 256, 0, stream>>>(
        Pcat + C_QA,  nullptr, LDP, 1 << 30, woRaT, 512, d_out, 1024, 512, 512);
}

// Round 2
// 357.155 us; speedup vs baseline: 1.5324x; 1.5324x over previous
//
#include <hip/hip_runtime.h>

typedef unsigned short u16;
typedef unsigned int u32;
typedef __attribute__((ext_vector_type(8))) short s16x8;
typedef __attribute__((ext_vector_type(4))) float f32x4;

// Pcat column offsets (bf16 projection buffer, 4096 rows x 4096 cols)
#define C_QSA 0
#define C_KSA 512
#define C_VSA 1024
#define C_QA  1536
#define C_KA  2048
#define C_QR  2560
#define C_KR  3072
#define C_SV  3584
#define LDP   4096
#define NROWS 4096   // B*S

__device__ __forceinline__ u16 f2bf(float f) {
    union { float f; unsigned u; } v; v.f = f;
    return (u16)((v.u + 0x7FFFu + ((v.u >> 16) & 1u)) >> 16);  // RNE
}
__device__ __forceinline__ float bf2f(u16 h) {
    union { unsigned u; float f; } v; v.u = ((unsigned)h) << 16; return v.f;
}
__device__ __forceinline__ float fexp(float y) {          // e^y
    return __builtin_exp2f(y * 1.4426950408889634f);
}
__device__ __forceinline__ float ftanh(float x) {         // exact formula, f32
    float e = __builtin_exp2f(x * 2.885390081777927f);    // exp(2x)
    return 1.f - 2.f / (e + 1.f);
}
__device__ __forceinline__ f32x4 mfma16(s16x8 a, s16x8 b, f32x4 c) {
    return __builtin_amdgcn_mfma_f32_16x16x32_bf16(a, b, c, 0, 0, 0);
}

// ---------------- converts / transposes ----------------

__global__ void cvt_f32_bf16(const float* __restrict__ in, u16* __restrict__ out, int n) {
    int i = (blockIdx.x * 256 + threadIdx.x) * 8;
    if (i >= n) return;
    float4 a = *(const float4*)(in + i);
    float4 b = *(const float4*)(in + i + 4);
    s16x8 o;
    o[0] = (short)f2bf(a.x); o[1] = (short)f2bf(a.y);
    o[2] = (short)f2bf(a.z); o[3] = (short)f2bf(a.w);
    o[4] = (short)f2bf(b.x); o[5] = (short)f2bf(b.y);
    o[6] = (short)f2bf(b.z); o[7] = (short)f2bf(b.w);
    *(s16x8*)(out + i) = o;
}

// fused tiled weight transpose: 10 weights, coalesced both sides
struct WP { const float* p[10]; };

__global__ void transpose_w(WP wp, u16* __restrict__ WcatT,
                            u16* __restrict__ woSaT, u16* __restrict__ woRaT) {
    const int z = blockIdx.z;
    const float* W;
    u16* Wt;
    int K;
    if (z < 8) { W = wp.p[z]; Wt = WcatT + (size_t)z * 524288; K = 1024; }
    else       { W = wp.p[z]; Wt = (z == 8) ? woSaT : woRaT;   K = 512;  }
    const int N = 512;
    const int kt = blockIdx.x * 32, nt = blockIdx.y * 32;
    if (kt >= K) return;
    __shared__ float t[32][33];
    const int c = threadIdx.x & 31, r0 = threadIdx.x >> 5;
#pragma unroll
    for (int it = 0; it < 4; ++it) {
        int r = it * 8 + r0;
        t[r][c] = W[(size_t)(kt + r) * N + nt + c];
    }
    __syncthreads();
#pragma unroll
    for (int it = 0; it < 4; ++it) {
        int r = it * 8 + r0;              // local n index
        Wt[(size_t)(nt + r) * K + kt + c] = f2bf(t[c][r]);
    }
}

// Vt[b][h][d][s] = Pcat[b*1024+s][colOff + h*64 + d], tiled/coalesced
__global__ void transpose_v2(const u16* __restrict__ P, u16* __restrict__ Vt, int colOff) {
    const int st = blockIdx.x * 32, ht = blockIdx.y * 32, b = blockIdx.z;
    __shared__ u16 t[32][34];
    const int c = threadIdx.x & 31, r0 = threadIdx.x >> 5;
#pragma unroll
    for (int it = 0; it < 4; ++it) {
        int r = it * 8 + r0;              // local s index
        t[r][c] = P[(size_t)(b * 1024 + st + r) * LDP + colOff + ht + c];
    }
    __syncthreads();
#pragma unroll
    for (int it = 0; it < 4; ++it) {
        int r = it * 8 + r0;              // local hd index
        Vt[(size_t)b * 524288 + (size_t)(ht + r) * 1024 + st + c] = t[c][r];
    }
}

// ---------------- RoPE (in-place on Pcat regions QSA,KSA,QA,KA) ----------------

__global__ void rope_kernel(u16* __restrict__ P, const float* __restrict__ fcos,
                            const float* __restrict__ fsin) {
    int idx = blockIdx.x * 256 + threadIdx.x;   // NROWS * 1024 pairs
    int row = idx >> 10;
    int rem = idx & 1023;
    int region = rem >> 8;                      // 0..3 -> {0,512,1536,2048}
    int pr = rem & 255;
    int head = pr >> 5, p = pr & 31;
    int off = (region + (region >> 1)) * 512;
    int col = off + head * 64 + 2 * p;
    int s = row & 1023;
    float c = fcos[s * 32 + p], sn = fsin[s * 32 + p];
    u32* ptr = (u32*)(P + (size_t)row * LDP + col);
    u32 v = *ptr;
    float xr = bf2f((u16)(v & 0xffff)), xi = bf2f((u16)(v >> 16));
    u16 o0 = f2bf(xr * c - xi * sn);
    u16 o1 = f2bf(xr * sn + xi * c);
    *ptr = (u32)o0 | ((u32)o1 << 16);
}

// ---------------- GEMM: C[M=4096][N] = A[M][K] @ Bt[N][K]^T ----------------
// 128x128 tile, BK=32, 4 waves (2x2 of 64x64), 16x16x32 bf16 MFMA.

template<bool OUT_BF16>
__global__ __launch_bounds__(256) void gemm_bf16(
    const u16* __restrict__ A, const u16* __restrict__ A2, int lda, int nswitch,
    const u16* __restrict__ Bt, int ldb,
    void* __restrict__ Cp, int ldc, int ccolOff, int K)
{
    __shared__ u16 As[128][40];
    __shared__ u16 Bs[128][40];
    const int tid = threadIdx.x;
    const int m0 = blockIdx.x * 128, n0 = blockIdx.y * 128;
    const u16* Ause = (A2 != nullptr && n0 >= nswitch) ? A2 : A;
    const int w = tid >> 6, lane = tid & 63;
    const int wm = (w >> 1) * 64, wn = (w & 1) * 64;
    const int lr = lane & 15, lg = lane >> 4;
    f32x4 acc[4][4] = {};

    for (int k0 = 0; k0 < K; k0 += 32) {
#pragma unroll
        for (int it = 0; it < 2; ++it) {
            int idx = tid + it * 256;
            int m = idx >> 2, seg = (idx & 3) * 8;
            *(s16x8*)&As[m][seg] = *(const s16x8*)&Ause[(size_t)(m0 + m) * lda + k0 + seg];
            *(s16x8*)&Bs[m][seg] = *(const s16x8*)&Bt[(size_t)(n0 + m) * ldb + k0 + seg];
        }
        __syncthreads();
        s16x8 af[4], bfr[4];
#pragma unroll
        for (int t = 0; t < 4; ++t) {
            af[t]  = *(const s16x8*)&As[wm + t * 16 + lr][lg * 8];
            bfr[t] = *(const s16x8*)&Bs[wn + t * 16 + lr][lg * 8];
        }
#pragma unroll
        for (int i = 0; i < 4; ++i)
#pragma unroll
            for (int j = 0; j < 4; ++j)
                acc[i][j] = mfma16(af[i], bfr[j], acc[i][j]);
        __syncthreads();
    }
#pragma unroll
    for (int i = 0; i < 4; ++i)
#pragma unroll
        for (int j = 0; j < 4; ++j)
#pragma unroll
            for (int r = 0; r < 4; ++r) {
                int row = m0 + wm + i * 16 + lg * 4 + r;
                int col = n0 + wn + j * 16 + lr;
                float val = acc[i][j][r];
                if (OUT_BF16)
                    ((u16*)Cp)[(size_t)row * ldc + ccolOff + col] = f2bf(val);
                else
                    ((float*)Cp)[(size_t)row * ldc + ccolOff + col] = val;
            }
}

// ---------------- SA flash attention: 1 wave per (b,h, paired i-tiles) ----------------

__global__ __launch_bounds__(64) void attn_sa(u16* __restrict__ P, const u16* __restrict__ Vt) {
    const int h = blockIdx.y, b = blockIdx.z;
    const int lane = threadIdx.x, lr = lane & 15, lg = lane >> 4;
    const size_t rowBase = (size_t)b * 1024;
    __shared__ u16 pl[16][40];

    const u16* Kbase = P + rowBase * LDP + (C_KSA + h * 64);
    const u16* Vb = Vt + ((size_t)(b * 8 + h)) * 65536;

    for (int tsel = 0; tsel < 2; ++tsel) {
        const int xt = tsel ? 63 - (int)blockIdx.x : (int)blockIdx.x;
        const int i0 = xt * 16;
        s16x8 qf[2];
        {
            const u16* q = P + (rowBase + i0 + lr) * LDP + (C_QSA + h * 64) + lg * 8;
            qf[0] = *(const s16x8*)q;
            qf[1] = *(const s16x8*)(q + 32);
        }
        f32x4 osum[4] = {};
        float m[4], l[4];
#pragma unroll
        for (int r = 0; r < 4; ++r) { m[r] = -1e30f; l[r] = 0.f; }
        const int njt = xt / 2 + 1;

        for (int jt = 0; jt < njt; ++jt) {
            int j0 = jt * 32;
            f32x4 sc[2] = {{0.f,0.f,0.f,0.f},{0.f,0.f,0.f,0.f}};
#pragma unroll
            for (int sub = 0; sub < 2; ++sub) {
                const u16* kp = Kbase + (size_t)(j0 + sub * 16 + lr) * LDP + lg * 8;
                s16x8 kf0 = *(const s16x8*)kp;
                s16x8 kf1 = *(const s16x8*)(kp + 32);
                sc[sub] = mfma16(qf[0], kf0, sc[sub]);
                sc[sub] = mfma16(qf[1], kf1, sc[sub]);
            }
#pragma unroll
            for (int sub = 0; sub < 2; ++sub)
#pragma unroll
                for (int r = 0; r < 4; ++r) {
                    int row = i0 + lg * 4 + r;
                    int col = j0 + sub * 16 + lr;
                    float v = sc[sub][r] * 0.125f;
                    sc[sub][r] = (col <= row) ? v : -1e30f;
                }
            float p0[4], p1[4], f[4];
#pragma unroll
            for (int r = 0; r < 4; ++r) {
                float v = fmaxf(sc[0][r], sc[1][r]);
                v = fmaxf(v, __shfl_xor(v, 1));
                v = fmaxf(v, __shfl_xor(v, 2));
                v = fmaxf(v, __shfl_xor(v, 4));
                v = fmaxf(v, __shfl_xor(v, 8));
                float mn = fmaxf(m[r], v);
                f[r] = fexp(m[r] - mn);
                m[r] = mn;
                p0[r] = fexp(sc[0][r] - mn);
                p1[r] = fexp(sc[1][r] - mn);
                float rs = p0[r] + p1[r];
                rs += __shfl_xor(rs, 1); rs += __shfl_xor(rs, 2);
                rs += __shfl_xor(rs, 4); rs += __shfl_xor(rs, 8);
                l[r] = l[r] * f[r] + rs;
            }
#pragma unroll
            for (int ds = 0; ds < 4; ++ds)
#pragma unroll
                for (int r = 0; r < 4; ++r) osum[ds][r] *= f[r];

            __syncthreads();
#pragma unroll
            for (int r = 0; r < 4; ++r) {
                pl[lg * 4 + r][lr]      = f2bf(p0[r]);
                pl[lg * 4 + r][16 + lr] = f2bf(p1[r]);
            }
            __syncthreads();
            s16x8 pa = *(const s16x8*)&pl[lr][lg * 8];
#pragma unroll
            for (int ds = 0; ds < 4; ++ds) {
                const u16* vp = Vb + (size_t)(ds * 16 + lr) * 1024 + j0 + lg * 8;
                s16x8 vb = *(const s16x8*)vp;
                osum[ds] = mfma16(pa, vb, osum[ds]);
            }
        }
#pragma unroll
        for (int ds = 0; ds < 4; ++ds)
#pragma unroll
            for (int r = 0; r < 4; ++r) {
                int row = i0 + lg * 4 + r;
                float v = osum[ds][r] / l[r];
                P[(rowBase + row) * LDP + (C_QSA + h * 64) + ds * 16 + lr] = f2bf(v);
            }
    }
}

// ---------------- RA attention: 4 waves/block, shared rel channels ----------------
// block = (i-tile pair, b, head-half). wave w: head 4*z+w, rel channels {2w,2w+1}.

__global__ __launch_bounds__(256) void attn_ra(u16* __restrict__ P, const u16* __restrict__ SVt,
                                               const float* __restrict__ wr) {
    const int w = threadIdx.x >> 6, lane = threadIdx.x & 63;
    const int lr = lane & 15, lg = lane >> 4;
    const int b = blockIdx.y;
    const int h = blockIdx.z * 4 + w;
    const int c0 = 2 * w;
    const size_t rowBase = (size_t)b * 1024;

    __shared__ float relT[8][16][33];   // [channel][i-local][j-local]
    __shared__ u16 pl[4][16][40];       // per-wave p staging

    const u16* Kbase  = P + rowBase * LDP + (C_KA + h * 64);
    const u16* KRbase = P + rowBase * LDP + C_KR;
    const u16* Vb = SVt + ((size_t)(b * 8 + h)) * 65536;

    for (int tsel = 0; tsel < 2; ++tsel) {
        const int xt = tsel ? 63 - (int)blockIdx.x : (int)blockIdx.x;
        const int i0 = xt * 16;
        s16x8 qf[2], qrf[2][2];
        {
            const u16* q = P + (rowBase + i0 + lr) * LDP + (C_QA + h * 64) + lg * 8;
            qf[0] = *(const s16x8*)q;
            qf[1] = *(const s16x8*)(q + 32);
        }
#pragma unroll
        for (int ci = 0; ci < 2; ++ci) {
            const u16* q = P + (rowBase + i0 + lr) * LDP + C_QR + (c0 + ci) * 64 + lg * 8;
            qrf[ci][0] = *(const s16x8*)q;
            qrf[ci][1] = *(const s16x8*)(q + 32);
        }
        f32x4 osum[4] = {};
        float relm[4][8] = {};
        float m[4], l[4];
#pragma unroll
        for (int r = 0; r < 4; ++r) { m[r] = -1e30f; l[r] = 0.f; }
        const int njt = xt / 2 + 1;

        for (int jt = 0; jt < njt; ++jt) {
            int j0 = jt * 32;
            // ---- QK^T for own head ----
            f32x4 sc[2] = {{0.f,0.f,0.f,0.f},{0.f,0.f,0.f,0.f}};
#pragma unroll
            for (int sub = 0; sub < 2; ++sub) {
                const u16* kp = Kbase + (size_t)(j0 + sub * 16 + lr) * LDP + lg * 8;
                s16x8 kf0 = *(const s16x8*)kp;
                s16x8 kf1 = *(const s16x8*)(kp + 32);
                sc[sub] = mfma16(qf[0], kf0, sc[sub]);
                sc[sub] = mfma16(qf[1], kf1, sc[sub]);
            }
            // ---- rel channels c0,c0+1 (computed once per block) ----
            f32x4 rt[2][2] = {};
#pragma unroll
            for (int ci = 0; ci < 2; ++ci)
#pragma unroll
                for (int sub = 0; sub < 2; ++sub) {
                    const u16* kp = KRbase + (size_t)(j0 + sub * 16 + lr) * LDP + (c0 + ci) * 64 + lg * 8;
                    s16x8 ka0 = *(const s16x8*)kp;
                    s16x8 ka1 = *(const s16x8*)(kp + 32);
                    rt[ci][sub] = mfma16(qrf[ci][0], ka0, rt[ci][sub]);
                    rt[ci][sub] = mfma16(qrf[ci][1], ka1, rt[ci][sub]);
                }
            // ---- mask + online softmax ----
#pragma unroll
            for (int sub = 0; sub < 2; ++sub)
#pragma unroll
                for (int r = 0; r < 4; ++r) {
                    int row = i0 + lg * 4 + r;
                    int col = j0 + sub * 16 + lr;
                    float v = sc[sub][r] * 0.125f;
                    sc[sub][r] = (col <= row) ? v : -1e30f;
                }
            float p0[4], p1[4], f[4];
#pragma unroll
            for (int r = 0; r < 4; ++r) {
                float v = fmaxf(sc[0][r], sc[1][r]);
                v = fmaxf(v, __shfl_xor(v, 1));
                v = fmaxf(v, __shfl_xor(v, 2));
                v = fmaxf(v, __shfl_xor(v, 4));
                v = fmaxf(v, __shfl_xor(v, 8));
                float mn = fmaxf(m[r], v);
                f[r] = fexp(m[r] - mn);
                m[r] = mn;
                p0[r] = fexp(sc[0][r] - mn);
                p1[r] = fexp(sc[1][r] - mn);
                float rs = p0[r] + p1[r];
                rs += __shfl_xor(rs, 1); rs += __shfl_xor(rs, 2);
                rs += __shfl_xor(rs, 4); rs += __shfl_xor(rs, 8);
                l[r] = l[r] * f[r] + rs;
            }
#pragma unroll
            for (int ds = 0; ds < 4; ++ds)
#pragma unroll
                for (int r = 0; r < 4; ++r) osum[ds][r] *= f[r];
#pragma unroll
            for (int r = 0; r < 4; ++r)
#pragma unroll
                for (int r8 = 0; r8 < 8; ++r8) relm[r][r8] *= f[r];

            // ---- publish tanh(rel) tiles + own p to LDS ----
            __syncthreads();   // prev iteration's relT reads complete
#pragma unroll
            for (int ci = 0; ci < 2; ++ci)
#pragma unroll
                for (int sub = 0; sub < 2; ++sub)
#pragma unroll
                    for (int r = 0; r < 4; ++r)
                        relT[c0 + ci][lg * 4 + r][sub * 16 + lr] = ftanh(rt[ci][sub][r] * 0.125f);
#pragma unroll
            for (int r = 0; r < 4; ++r) {
                pl[w][lg * 4 + r][lr]      = f2bf(p0[r]);
                pl[w][lg * 4 + r][16 + lr] = f2bf(p1[r]);
            }
            __syncthreads();   // relT + pl ready

            // ---- accumulate rel message from all 8 channels ----
#pragma unroll
            for (int r8 = 0; r8 < 8; ++r8)
#pragma unroll
                for (int r = 0; r < 4; ++r) {
                    float t0 = relT[r8][lg * 4 + r][lr];
                    float t1 = relT[r8][lg * 4 + r][16 + lr];
                    relm[r][r8] += p0[r] * t0 + p1[r] * t1;
                }

            // ---- PV ----
            s16x8 pa = *(const s16x8*)&pl[w][lr][lg * 8];
#pragma unroll
            for (int ds = 0; ds < 4; ++ds) {
                const u16* vp = Vb + (size_t)(ds * 16 + lr) * 1024 + j0 + lg * 8;
                s16x8 vb = *(const s16x8*)vp;
                osum[ds] = mfma16(pa, vb, osum[ds]);
            }
        }

        // ---- epilogue: reduce relm over j-lanes, project with wr, write ----
#pragma unroll
        for (int r = 0; r < 4; ++r)
#pragma unroll
            for (int r8 = 0; r8 < 8; ++r8) {
                float v = relm[r][r8];
                v += __shfl_xor(v, 1); v += __shfl_xor(v, 2);
                v += __shfl_xor(v, 4); v += __shfl_xor(v, 8);
                relm[r][r8] = v / l[r];
            }
#pragma unroll
        for (int ds = 0; ds < 4; ++ds) {
            int d = ds * 16 + lr;
            float wrv[8];
#pragma unroll
            for (int r8 = 0; r8 < 8; ++r8) wrv[r8] = wr[h * 512 + d * 8 + r8];
#pragma unroll
            for (int r = 0; r < 4; ++r) {
                float v = osum[ds][r] / l[r];
#pragma unroll
                for (int r8 = 0; r8 < 8; ++r8) v += relm[r][r8] * wrv[r8];
                P[(rowBase + i0 + lg * 4 + r) * LDP + (C_QA + h * 64) + d] = f2bf(v);
            }
        }
    }
}

// ---------------- launcher ----------------

extern "C" void kernel_launch(void* const* d_in, const int* in_sizes, int n_in,
                              void* d_out, int out_size, void* d_ws, size_t ws_size,
                              hipStream_t stream)
{
    const float* x     = (const float*)d_in[0];
    const float* sym   = (const float*)d_in[1];
    const float* fcos  = (const float*)d_in[2];
    const float* fsin  = (const float*)d_in[3];
    const float* w_qsa = (const float*)d_in[4];
    const float* w_ksa = (const float*)d_in[5];
    const float* w_vsa = (const float*)d_in[6];
    const float* w_osa = (const float*)d_in[7];
    const float* w_qa  = (const float*)d_in[8];
    const float* w_ka  = (const float*)d_in[9];
    const float* w_qr  = (const float*)d_in[10];
    const float* w_kr  = (const float*)d_in[11];
    const float* wr    = (const float*)d_in[12];
    const float* w_sv  = (const float*)d_in[13];
    const float* w_ora = (const float*)d_in[14];

    char* ws = (char*)d_ws;
    u16* xb    = (u16*)(ws);                                  // 8 MB
    u16* symb  = (u16*)(ws + (8u  << 20));                    // 8 MB
    u16* WcatT = (u16*)(ws + (16u << 20));                    // 8 MB (4096 x 1024)
    u16* woSaT = (u16*)(ws + (24u << 20));                    // 512 KB
    u16* woRaT = (u16*)(ws + (24u << 20) + (512u << 10));     // 512 KB
    u16* Pcat  = (u16*)(ws + (25u << 20));                    // 32 MB (4096 x 4096)
    u16* vT    = (u16*)(ws + (57u << 20));                    // 4 MB
    u16* svT   = (u16*)(ws + (61u << 20));                    // 4 MB

    // bf16 converts
    cvt_f32_bf16<<<2048, 256, 0, stream>>>(x,   xb,   4194304);
    cvt_f32_bf16<<<2048, 256, 0, stream>>>(sym, symb, 4194304);

    // fused coalesced weight transposes (order matches Pcat region order)
    WP wp{{w_qsa, w_ksa, w_vsa, w_qa, w_ka, w_qr, w_kr, w_sv, w_osa, w_ora}};
    transpose_w<<<dim3(32, 16, 10), 256, 0, stream>>>(wp, WcatT, woSaT, woRaT);

    // fused projection GEMM: Pcat[4096][4096]; A = xb except SV columns use symb
    gemm_bf16<true><<<dim3(32, 32), 256, 0, stream>>>(
        xb, symb, 1024, C_SV, WcatT, 1024, Pcat, LDP, 0, 1024);

    // RoPE in place on q_sa, k_sa, qa, ka
    rope_kernel<<<16384, 256, 0, stream>>>(Pcat, fcos, fsin);

    // V / SV transposed copies for the PV MFMA B-operand
    transpose_v2<<<dim3(32, 16, 4), 256, 0, stream>>>(Pcat, vT,  C_VSA);
    transpose_v2<<<dim3(32, 16, 4), 256, 0, stream>>>(Pcat, svT, C_SV);

    // attention (outputs alias dead q_sa / qa column regions)
    attn_sa<<<dim3(32, 8, 4), 64, 0, stream>>>(Pcat, vT);
    attn_ra<<<dim3(32, 4, 2), 256, 0, stream>>>(Pcat, svT, wr);

    // output projections straight into f32 d_out (ldc = 1024)
    gemm_bf16<false><<<dim3(32, 4), 256, 0, stream>>>(
        Pcat + C_QSA, nullptr, LDP, 1 << 30, woSaT, 512, d_out, 1024, 0,   512);
    gemm_bf16<false><<<dim3(32, 4), 256, 0, stream>>>(
        Pcat + C_QA,  nullptr, LDP, 1 << 30, woRaT, 512, d_out, 1024, 512, 512);
}

// Round 3
// 302.761 us; speedup vs baseline: 1.8077x; 1.1797x over previous
//
#include <hip/hip_runtime.h>

typedef unsigned short u16;
typedef unsigned int u32;
typedef __attribute__((ext_vector_type(8))) short s16x8;
typedef __attribute__((ext_vector_type(4))) float f32x4;

// Pcat column offsets (bf16 projection buffer, 4096 rows x 4096 cols)
#define C_QSA 0
#define C_KSA 512
#define C_VSA 1024
#define C_QA  1536
#define C_KA  2048
#define C_QR  2560
#define C_KR  3072
#define C_SV  3584
#define LDP   4096
#define NROWS 4096   // B*S

__device__ __forceinline__ u16 f2bf(float f) {
    union { float f; unsigned u; } v; v.f = f;
    return (u16)((v.u + 0x7FFFu + ((v.u >> 16) & 1u)) >> 16);  // RNE
}
__device__ __forceinline__ float bf2f(u16 h) {
    union { unsigned u; float f; } v; v.u = ((unsigned)h) << 16; return v.f;
}
__device__ __forceinline__ float fexp(float y) {          // e^y
    return __builtin_exp2f(y * 1.4426950408889634f);
}
__device__ __forceinline__ float ftanh(float x) {         // exact formula, f32
    float e = __builtin_exp2f(x * 2.885390081777927f);    // exp(2x)
    return 1.f - 2.f / (e + 1.f);
}
__device__ __forceinline__ f32x4 mfma16(s16x8 a, s16x8 b, f32x4 c) {
    return __builtin_amdgcn_mfma_f32_16x16x32_bf16(a, b, c, 0, 0, 0);
}

// ---------------- converts / transposes ----------------

__global__ void cvt_f32_bf16(const float* __restrict__ in, u16* __restrict__ out, int n) {
    int i = (blockIdx.x * 256 + threadIdx.x) * 8;
    if (i >= n) return;
    float4 a = *(const float4*)(in + i);
    float4 b = *(const float4*)(in + i + 4);
    s16x8 o;
    o[0] = (short)f2bf(a.x); o[1] = (short)f2bf(a.y);
    o[2] = (short)f2bf(a.z); o[3] = (short)f2bf(a.w);
    o[4] = (short)f2bf(b.x); o[5] = (short)f2bf(b.y);
    o[6] = (short)f2bf(b.z); o[7] = (short)f2bf(b.w);
    *(s16x8*)(out + i) = o;
}

// fused tiled weight transpose: 10 weights, coalesced both sides
struct WP { const float* p[10]; };

__global__ void transpose_w(WP wp, u16* __restrict__ WcatT,
                            u16* __restrict__ woSaT, u16* __restrict__ woRaT) {
    const int z = blockIdx.z;
    const float* W;
    u16* Wt;
    int K;
    if (z < 8) { W = wp.p[z]; Wt = WcatT + (size_t)z * 524288; K = 1024; }
    else       { W = wp.p[z]; Wt = (z == 8) ? woSaT : woRaT;   K = 512;  }
    const int N = 512;
    const int kt = blockIdx.x * 32, nt = blockIdx.y * 32;
    if (kt >= K) return;
    __shared__ float t[32][33];
    const int c = threadIdx.x & 31, r0 = threadIdx.x >> 5;
#pragma unroll
    for (int it = 0; it < 4; ++it) {
        int r = it * 8 + r0;
        t[r][c] = W[(size_t)(kt + r) * N + nt + c];
    }
    __syncthreads();
#pragma unroll
    for (int it = 0; it < 4; ++it) {
        int r = it * 8 + r0;              // local n index
        Wt[(size_t)(nt + r) * K + kt + c] = f2bf(t[c][r]);
    }
}

// Vt[b][h][d][s] = Pcat[b*1024+s][colOff + h*64 + d], tiled/coalesced
__global__ void transpose_v2(const u16* __restrict__ P, u16* __restrict__ Vt, int colOff) {
    const int st = blockIdx.x * 32, ht = blockIdx.y * 32, b = blockIdx.z;
    __shared__ u16 t[32][34];
    const int c = threadIdx.x & 31, r0 = threadIdx.x >> 5;
#pragma unroll
    for (int it = 0; it < 4; ++it) {
        int r = it * 8 + r0;              // local s index
        t[r][c] = P[(size_t)(b * 1024 + st + r) * LDP + colOff + ht + c];
    }
    __syncthreads();
#pragma unroll
    for (int it = 0; it < 4; ++it) {
        int r = it * 8 + r0;              // local hd index
        Vt[(size_t)b * 524288 + (size_t)(ht + r) * 1024 + st + c] = t[c][r];
    }
}

// ---------------- RoPE (in-place on Pcat regions QSA,KSA,QA,KA) ----------------

__global__ void rope_kernel(u16* __restrict__ P, const float* __restrict__ fcos,
                            const float* __restrict__ fsin) {
    int idx = blockIdx.x * 256 + threadIdx.x;   // NROWS * 1024 pairs
    int row = idx >> 10;
    int rem = idx & 1023;
    int region = rem >> 8;                      // 0..3 -> {0,512,1536,2048}
    int pr = rem & 255;
    int head = pr >> 5, p = pr & 31;
    int off = (region + (region >> 1)) * 512;
    int col = off + head * 64 + 2 * p;
    int s = row & 1023;
    float c = fcos[s * 32 + p], sn = fsin[s * 32 + p];
    u32* ptr = (u32*)(P + (size_t)row * LDP + col);
    u32 v = *ptr;
    float xr = bf2f((u16)(v & 0xffff)), xi = bf2f((u16)(v >> 16));
    u16 o0 = f2bf(xr * c - xi * sn);
    u16 o1 = f2bf(xr * sn + xi * c);
    *ptr = (u32)o0 | ((u32)o1 << 16);
}

// ---------------- GEMM: C[M=4096][N] = A[M][K] @ Bt[N][K]^T ----------------
// 128x128 tile, BK=32, 4 waves (2x2 of 64x64), 16x16x32 bf16 MFMA.

template<bool OUT_BF16>
__global__ __launch_bounds__(256) void gemm_bf16(
    const u16* __restrict__ A, const u16* __restrict__ A2, int lda, int nswitch,
    const u16* __restrict__ Bt, int ldb,
    void* __restrict__ Cp, int ldc, int ccolOff, int K)
{
    __shared__ u16 As[128][40];
    __shared__ u16 Bs[128][40];
    const int tid = threadIdx.x;
    const int m0 = blockIdx.x * 128, n0 = blockIdx.y * 128;
    const u16* Ause = (A2 != nullptr && n0 >= nswitch) ? A2 : A;
    const int w = tid >> 6, lane = tid & 63;
    const int wm = (w >> 1) * 64, wn = (w & 1) * 64;
    const int lr = lane & 15, lg = lane >> 4;
    f32x4 acc[4][4] = {};

    for (int k0 = 0; k0 < K; k0 += 32) {
#pragma unroll
        for (int it = 0; it < 2; ++it) {
            int idx = tid + it * 256;
            int m = idx >> 2, seg = (idx & 3) * 8;
            *(s16x8*)&As[m][seg] = *(const s16x8*)&Ause[(size_t)(m0 + m) * lda + k0 + seg];
            *(s16x8*)&Bs[m][seg] = *(const s16x8*)&Bt[(size_t)(n0 + m) * ldb + k0 + seg];
        }
        __syncthreads();
        s16x8 af[4], bfr[4];
#pragma unroll
        for (int t = 0; t < 4; ++t) {
            af[t]  = *(const s16x8*)&As[wm + t * 16 + lr][lg * 8];
            bfr[t] = *(const s16x8*)&Bs[wn + t * 16 + lr][lg * 8];
        }
#pragma unroll
        for (int i = 0; i < 4; ++i)
#pragma unroll
            for (int j = 0; j < 4; ++j)
                acc[i][j] = mfma16(af[i], bfr[j], acc[i][j]);
        __syncthreads();
    }
#pragma unroll
    for (int i = 0; i < 4; ++i)
#pragma unroll
        for (int j = 0; j < 4; ++j)
#pragma unroll
            for (int r = 0; r < 4; ++r) {
                int row = m0 + wm + i * 16 + lg * 4 + r;
                int col = n0 + wn + j * 16 + lr;
                float val = acc[i][j][r];
                if (OUT_BF16)
                    ((u16*)Cp)[(size_t)row * ldc + ccolOff + col] = f2bf(val);
                else
                    ((float*)Cp)[(size_t)row * ldc + ccolOff + col] = val;
            }
}

// ---------------- SA flash attention ----------------
// 1 wave per (b,h,i-tile). 1-D grid 2048: bid&7 = h (XCD affinity),
// bid>>5 heavy-first i-tile, (bid>>3)&3 = b.

__global__ __launch_bounds__(64) void attn_sa(u16* __restrict__ P, const u16* __restrict__ Vt) {
    const int bid = blockIdx.x;
    const int h = bid & 7;
    const int b = (bid >> 3) & 3;
    const int xt = 63 - (bid >> 5);
    const int lane = threadIdx.x, lr = lane & 15, lg = lane >> 4;
    const size_t rowBase = (size_t)b * 1024;
    __shared__ u16 pl[16][40];

    const u16* Kbase = P + rowBase * LDP + (C_KSA + h * 64);
    const u16* Vb = Vt + ((size_t)(b * 8 + h)) * 65536;
    const int i0 = xt * 16;

    s16x8 qf[2];
    {
        const u16* q = P + (rowBase + i0 + lr) * LDP + (C_QSA + h * 64) + lg * 8;
        qf[0] = *(const s16x8*)q;
        qf[1] = *(const s16x8*)(q + 32);
    }
    f32x4 osum[4] = {};
    float m[4], l[4];
#pragma unroll
    for (int r = 0; r < 4; ++r) { m[r] = -1e30f; l[r] = 0.f; }
    const int njt = xt / 2 + 1;

    for (int jt = 0; jt < njt; ++jt) {
        int j0 = jt * 32;
        // ---- issue ALL global loads for this tile up front ----
        s16x8 kf[2][2], vf[4];
#pragma unroll
        for (int sub = 0; sub < 2; ++sub) {
            const u16* kp = Kbase + (size_t)(j0 + sub * 16 + lr) * LDP + lg * 8;
            kf[sub][0] = *(const s16x8*)kp;
            kf[sub][1] = *(const s16x8*)(kp + 32);
        }
#pragma unroll
        for (int ds = 0; ds < 4; ++ds)
            vf[ds] = *(const s16x8*)(Vb + (size_t)(ds * 16 + lr) * 1024 + j0 + lg * 8);

        f32x4 sc[2] = {{0.f,0.f,0.f,0.f},{0.f,0.f,0.f,0.f}};
#pragma unroll
        for (int sub = 0; sub < 2; ++sub) {
            sc[sub] = mfma16(qf[0], kf[sub][0], sc[sub]);
            sc[sub] = mfma16(qf[1], kf[sub][1], sc[sub]);
        }
#pragma unroll
        for (int sub = 0; sub < 2; ++sub)
#pragma unroll
            for (int r = 0; r < 4; ++r) {
                int row = i0 + lg * 4 + r;
                int col = j0 + sub * 16 + lr;
                float v = sc[sub][r] * 0.125f;
                sc[sub][r] = (col <= row) ? v : -1e30f;
            }
        float p0[4], p1[4], f[4];
#pragma unroll
        for (int r = 0; r < 4; ++r) {
            float v = fmaxf(sc[0][r], sc[1][r]);
            v = fmaxf(v, __shfl_xor(v, 1));
            v = fmaxf(v, __shfl_xor(v, 2));
            v = fmaxf(v, __shfl_xor(v, 4));
            v = fmaxf(v, __shfl_xor(v, 8));
            float mn = fmaxf(m[r], v);
            f[r] = fexp(m[r] - mn);
            m[r] = mn;
            p0[r] = fexp(sc[0][r] - mn);
            p1[r] = fexp(sc[1][r] - mn);
            float rs = p0[r] + p1[r];
            rs += __shfl_xor(rs, 1); rs += __shfl_xor(rs, 2);
            rs += __shfl_xor(rs, 4); rs += __shfl_xor(rs, 8);
            l[r] = l[r] * f[r] + rs;
        }
#pragma unroll
        for (int ds = 0; ds < 4; ++ds)
#pragma unroll
            for (int r = 0; r < 4; ++r) osum[ds][r] *= f[r];

        __syncthreads();
#pragma unroll
        for (int r = 0; r < 4; ++r) {
            pl[lg * 4 + r][lr]      = f2bf(p0[r]);
            pl[lg * 4 + r][16 + lr] = f2bf(p1[r]);
        }
        __syncthreads();
        s16x8 pa = *(const s16x8*)&pl[lr][lg * 8];
#pragma unroll
        for (int ds = 0; ds < 4; ++ds)
            osum[ds] = mfma16(pa, vf[ds], osum[ds]);
    }
#pragma unroll
    for (int ds = 0; ds < 4; ++ds)
#pragma unroll
        for (int r = 0; r < 4; ++r) {
            int row = i0 + lg * 4 + r;
            float v = osum[ds][r] / l[r];
            P[(rowBase + row) * LDP + (C_QSA + h * 64) + ds * 16 + lr] = f2bf(v);
        }
}

// ---------------- RA attention: 4 waves/block, shared rel channels ----------------
// 1-D grid 512: bid&7 = (b, head-half) -> XCD affinity; bid>>3 heavy-first i-tile.
// wave w: head 4*hh+w, rel channels {2w,2w+1} (each channel computed once/block).

__global__ __launch_bounds__(256) void attn_ra(u16* __restrict__ P, const u16* __restrict__ SVt,
                                               const float* __restrict__ wr) {
    const int bid = blockIdx.x;
    const int slot = bid & 7;
    const int b = slot & 3, hh = slot >> 2;
    const int xt = 63 - (bid >> 3);
    const int w = threadIdx.x >> 6, lane = threadIdx.x & 63;
    const int lr = lane & 15, lg = lane >> 4;
    const int h = hh * 4 + w;
    const int c0 = 2 * w;
    const size_t rowBase = (size_t)b * 1024;
    const int i0 = xt * 16;

    __shared__ float relT[8][16][33];   // [channel][i-local][j-local]
    __shared__ u16 pl[4][16][40];       // per-wave p staging

    const u16* Kbase  = P + rowBase * LDP + (C_KA + h * 64);
    const u16* KRbase = P + rowBase * LDP + C_KR;
    const u16* Vb = SVt + ((size_t)(b * 8 + h)) * 65536;

    s16x8 qf[2], qrf[2][2];
    {
        const u16* q = P + (rowBase + i0 + lr) * LDP + (C_QA + h * 64) + lg * 8;
        qf[0] = *(const s16x8*)q;
        qf[1] = *(const s16x8*)(q + 32);
    }
#pragma unroll
    for (int ci = 0; ci < 2; ++ci) {
        const u16* q = P + (rowBase + i0 + lr) * LDP + C_QR + (c0 + ci) * 64 + lg * 8;
        qrf[ci][0] = *(const s16x8*)q;
        qrf[ci][1] = *(const s16x8*)(q + 32);
    }
    f32x4 osum[4] = {};
    float relm[4][8] = {};
    float m[4], l[4];
#pragma unroll
    for (int r = 0; r < 4; ++r) { m[r] = -1e30f; l[r] = 0.f; }
    const int njt = xt / 2 + 1;

    for (int jt = 0; jt < njt; ++jt) {
        int j0 = jt * 32;
        // ---- issue ALL global loads for this tile up front ----
        s16x8 kf[2][2], krf[2][2][2], vf[4];
#pragma unroll
        for (int sub = 0; sub < 2; ++sub) {
            const u16* kp = Kbase + (size_t)(j0 + sub * 16 + lr) * LDP + lg * 8;
            kf[sub][0] = *(const s16x8*)kp;
            kf[sub][1] = *(const s16x8*)(kp + 32);
        }
#pragma unroll
        for (int ci = 0; ci < 2; ++ci)
#pragma unroll
            for (int sub = 0; sub < 2; ++sub) {
                const u16* kp = KRbase + (size_t)(j0 + sub * 16 + lr) * LDP + (c0 + ci) * 64 + lg * 8;
                krf[ci][sub][0] = *(const s16x8*)kp;
                krf[ci][sub][1] = *(const s16x8*)(kp + 32);
            }
#pragma unroll
        for (int ds = 0; ds < 4; ++ds)
            vf[ds] = *(const s16x8*)(Vb + (size_t)(ds * 16 + lr) * 1024 + j0 + lg * 8);

        // ---- QK^T for own head ----
        f32x4 sc[2] = {{0.f,0.f,0.f,0.f},{0.f,0.f,0.f,0.f}};
#pragma unroll
        for (int sub = 0; sub < 2; ++sub) {
            sc[sub] = mfma16(qf[0], kf[sub][0], sc[sub]);
            sc[sub] = mfma16(qf[1], kf[sub][1], sc[sub]);
        }
        // ---- rel channels c0,c0+1 (computed once per block) ----
        f32x4 rt[2][2] = {};
#pragma unroll
        for (int ci = 0; ci < 2; ++ci)
#pragma unroll
            for (int sub = 0; sub < 2; ++sub) {
                rt[ci][sub] = mfma16(qrf[ci][0], krf[ci][sub][0], rt[ci][sub]);
                rt[ci][sub] = mfma16(qrf[ci][1], krf[ci][sub][1], rt[ci][sub]);
            }
        // ---- mask + online softmax ----
#pragma unroll
        for (int sub = 0; sub < 2; ++sub)
#pragma unroll
            for (int r = 0; r < 4; ++r) {
                int row = i0 + lg * 4 + r;
                int col = j0 + sub * 16 + lr;
                float v = sc[sub][r] * 0.125f;
                sc[sub][r] = (col <= row) ? v : -1e30f;
            }
        float p0[4], p1[4], f[4];
#pragma unroll
        for (int r = 0; r < 4; ++r) {
            float v = fmaxf(sc[0][r], sc[1][r]);
            v = fmaxf(v, __shfl_xor(v, 1));
            v = fmaxf(v, __shfl_xor(v, 2));
            v = fmaxf(v, __shfl_xor(v, 4));
            v = fmaxf(v, __shfl_xor(v, 8));
            float mn = fmaxf(m[r], v);
            f[r] = fexp(m[r] - mn);
            m[r] = mn;
            p0[r] = fexp(sc[0][r] - mn);
            p1[r] = fexp(sc[1][r] - mn);
            float rs = p0[r] + p1[r];
            rs += __shfl_xor(rs, 1); rs += __shfl_xor(rs, 2);
            rs += __shfl_xor(rs, 4); rs += __shfl_xor(rs, 8);
            l[r] = l[r] * f[r] + rs;
        }
#pragma unroll
        for (int ds = 0; ds < 4; ++ds)
#pragma unroll
            for (int r = 0; r < 4; ++r) osum[ds][r] *= f[r];
#pragma unroll
        for (int r = 0; r < 4; ++r)
#pragma unroll
            for (int r8 = 0; r8 < 8; ++r8) relm[r][r8] *= f[r];

        // ---- publish tanh(rel) tiles + own p to LDS ----
        __syncthreads();   // prev iteration's relT reads complete
#pragma unroll
        for (int ci = 0; ci < 2; ++ci)
#pragma unroll
            for (int sub = 0; sub < 2; ++sub)
#pragma unroll
                for (int r = 0; r < 4; ++r)
                    relT[c0 + ci][lg * 4 + r][sub * 16 + lr] = ftanh(rt[ci][sub][r] * 0.125f);
#pragma unroll
        for (int r = 0; r < 4; ++r) {
            pl[w][lg * 4 + r][lr]      = f2bf(p0[r]);
            pl[w][lg * 4 + r][16 + lr] = f2bf(p1[r]);
        }
        __syncthreads();   // relT + pl ready

        // ---- accumulate rel message from all 8 channels ----
#pragma unroll
        for (int r8 = 0; r8 < 8; ++r8)
#pragma unroll
            for (int r = 0; r < 4; ++r) {
                float t0 = relT[r8][lg * 4 + r][lr];
                float t1 = relT[r8][lg * 4 + r][16 + lr];
                relm[r][r8] += p0[r] * t0 + p1[r] * t1;
            }

        // ---- PV ----
        s16x8 pa = *(const s16x8*)&pl[w][lr][lg * 8];
#pragma unroll
        for (int ds = 0; ds < 4; ++ds)
            osum[ds] = mfma16(pa, vf[ds], osum[ds]);
    }

    // ---- epilogue: reduce relm over j-lanes, project with wr, write ----
#pragma unroll
    for (int r = 0; r < 4; ++r)
#pragma unroll
        for (int r8 = 0; r8 < 8; ++r8) {
            float v = relm[r][r8];
            v += __shfl_xor(v, 1); v += __shfl_xor(v, 2);
            v += __shfl_xor(v, 4); v += __shfl_xor(v, 8);
            relm[r][r8] = v / l[r];
        }
#pragma unroll
    for (int ds = 0; ds < 4; ++ds) {
        int d = ds * 16 + lr;
        float wrv[8];
#pragma unroll
        for (int r8 = 0; r8 < 8; ++r8) wrv[r8] = wr[h * 512 + d * 8 + r8];
#pragma unroll
        for (int r = 0; r < 4; ++r) {
            float v = osum[ds][r] / l[r];
#pragma unroll
            for (int r8 = 0; r8 < 8; ++r8) v += relm[r][r8] * wrv[r8];
            P[(rowBase + i0 + lg * 4 + r) * LDP + (C_QA + h * 64) + d] = f2bf(v);
        }
    }
}

// ---------------- launcher ----------------

extern "C" void kernel_launch(void* const* d_in, const int* in_sizes, int n_in,
                              void* d_out, int out_size, void* d_ws, size_t ws_size,
                              hipStream_t stream)
{
    const float* x     = (const float*)d_in[0];
    const float* sym   = (const float*)d_in[1];
    const float* fcos  = (const float*)d_in[2];
    const float* fsin  = (const float*)d_in[3];
    const float* w_qsa = (const float*)d_in[4];
    const float* w_ksa = (const float*)d_in[5];
    const float* w_vsa = (const float*)d_in[6];
    const float* w_osa = (const float*)d_in[7];
    const float* w_qa  = (const float*)d_in[8];
    const float* w_ka  = (const float*)d_in[9];
    const float* w_qr  = (const float*)d_in[10];
    const float* w_kr  = (const float*)d_in[11];
    const float* wr    = (const float*)d_in[12];
    const float* w_sv  = (const float*)d_in[13];
    const float* w_ora = (const float*)d_in[14];

    char* ws = (char*)d_ws;
    u16* xb    = (u16*)(ws);                                  // 8 MB
    u16* symb  = (u16*)(ws + (8u  << 20));                    // 8 MB
    u16* WcatT = (u16*)(ws + (16u << 20));                    // 8 MB (4096 x 1024)
    u16* woSaT = (u16*)(ws + (24u << 20));                    // 512 KB
    u16* woRaT = (u16*)(ws + (24u << 20) + (512u << 10));     // 512 KB
    u16* Pcat  = (u16*)(ws + (25u << 20));                    // 32 MB (4096 x 4096)
    u16* vT    = (u16*)(ws + (57u << 20));                    // 4 MB
    u16* svT   = (u16*)(ws + (61u << 20));                    // 4 MB

    // bf16 converts
    cvt_f32_bf16<<<2048, 256, 0, stream>>>(x,   xb,   4194304);
    cvt_f32_bf16<<<2048, 256, 0, stream>>>(sym, symb, 4194304);

    // fused coalesced weight transposes (order matches Pcat region order)
    WP wp{{w_qsa, w_ksa, w_vsa, w_qa, w_ka, w_qr, w_kr, w_sv, w_osa, w_ora}};
    transpose_w<<<dim3(32, 16, 10), 256, 0, stream>>>(wp, WcatT, woSaT, woRaT);

    // fused projection GEMM: Pcat[4096][4096]; A = xb except SV columns use symb
    gemm_bf16<true><<<dim3(32, 32), 256, 0, stream>>>(
        xb, symb, 1024, C_SV, WcatT, 1024, Pcat, LDP, 0, 1024);

    // RoPE in place on q_sa, k_sa, qa, ka
    rope_kernel<<<16384, 256, 0, stream>>>(Pcat, fcos, fsin);

    // V / SV transposed copies for the PV MFMA B-operand
    transpose_v2<<<dim3(32, 16, 4), 256, 0, stream>>>(Pcat, vT,  C_VSA);
    transpose_v2<<<dim3(32, 16, 4), 256, 0, stream>>>(Pcat, svT, C_SV);

    // attention (outputs alias dead q_sa / qa column regions)
    attn_sa<<<2048, 64, 0, stream>>>(Pcat, vT);
    attn_ra<<<512, 256, 0, stream>>>(Pcat, svT, wr);

    // output projections straight into f32 d_out (ldc = 1024)
    gemm_bf16<false><<<dim3(32, 4), 256, 0, stream>>>(
        Pcat + C_QSA, nullptr, LDP, 1 << 30, woSaT, 512, d_out, 1024, 0,   512);
    gemm_bf16<false><<<dim3(32, 4), 256, 0, stream>>>(
        Pcat + C_QA,  nullptr, LDP, 1 << 30, woRaT, 512, d_out, 1024, 512, 512);
}